// Round 1
// baseline (70.173 us; speedup 1.0000x reference)
//
#include <hip/hip_runtime.h>
#include <math.h>

// Problem constants (from reference): B=65536, N=512, N_IN=64, N_OUT=16.
// Effective op: out[b,j] = act(x[b,:64] @ W[:64, 496+j] + bias[496+j]).

typedef __bf16 bf16x8 __attribute__((ext_vector_type(8)));
typedef float floatx4 __attribute__((ext_vector_type(4)));

#define NN_N 512
#define NN_NIN 64
#define NN_NOUT 16

__global__ __launch_bounds__(256) void NeuralNetwork_74466142978489_kernel(
    const float* __restrict__ x,     // [B, 64]
    const float* __restrict__ W,     // [512, 512] row-major
    const float* __restrict__ bias,  // [512]
    const int*   __restrict__ acts,  // [512]
    float* __restrict__ out,         // [B, 16]
    int num_tiles)                   // B / 16
{
    const int lane = threadIdx.x & 63;
    const int wave = (int)((blockIdx.x * blockDim.x + threadIdx.x) >> 6);
    const int nwaves = (int)((gridDim.x * blockDim.x) >> 6);
    const int m    = lane & 15;   // A-row within tile / D-col index n
    const int quad = lane >> 4;
    const int col  = m;                        // output column n
    const int gcol = NN_N - NN_NOUT + col;     // 496 + n

    // --- B fragment: W[k, 496+n] as bf16, k = t*32 + quad*8 + j. Built once;
    // W slice is 64x16 floats (4 KB), L2/L3-hot across all 4096 waves.
    bf16x8 bfrag0, bfrag1;
#pragma unroll
    for (int j = 0; j < 8; ++j) {
        int k0 = quad * 8 + j;
        bfrag0[j] = (__bf16)W[(size_t)k0 * NN_N + gcol];
        bfrag1[j] = (__bf16)W[(size_t)(k0 + 32) * NN_N + gcol];
    }
    const float bval = bias[gcol];
    const int aid = acts[gcol];

    for (int tile = wave; tile < num_tiles; tile += nwaves) {
        const float* row = x + (size_t)(tile * 16 + m) * NN_NIN;

        floatx4 acc = {bval, bval, bval, bval};
#pragma unroll
        for (int t = 0; t < 2; ++t) {
            // A fragment: x[tile*16+m, k], k = t*32 + quad*8 + j (8 consecutive)
            const float4 a0 = *(const float4*)(row + t * 32 + quad * 8);
            const float4 a1 = *(const float4*)(row + t * 32 + quad * 8 + 4);
            bf16x8 afrag;
            afrag[0] = (__bf16)a0.x; afrag[1] = (__bf16)a0.y;
            afrag[2] = (__bf16)a0.z; afrag[3] = (__bf16)a0.w;
            afrag[4] = (__bf16)a1.x; afrag[5] = (__bf16)a1.y;
            afrag[6] = (__bf16)a1.z; afrag[7] = (__bf16)a1.w;
            acc = __builtin_amdgcn_mfma_f32_16x16x32_bf16(
                afrag, (t == 0) ? bfrag0 : bfrag1, acc, 0, 0, 0);
        }

        // D layout: col = lane&15, row = quad*4 + r. Apply per-column activation.
#pragma unroll
        for (int r = 0; r < 4; ++r) {
            float v = acc[r];
            float y;
            if (aid == 0) {
                // tanh, overflow-stable both directions
                y = 1.0f - 2.0f / (__expf(2.0f * v) + 1.0f);
            } else if (aid == 1) {
                y = 1.0f / (1.0f + __expf(-v));
            } else if (aid == 2) {
                y = v > 0.0f ? v : 0.0f;
            } else if (aid == 3) {
                y = v > 0.0f ? v : 0.01f * v;
            } else {
                y = v;
            }
            out[(size_t)(tile * 16 + quad * 4 + r) * NN_NOUT + col] = y;
        }
    }
}

extern "C" void kernel_launch(void* const* d_in, const int* in_sizes, int n_in,
                              void* d_out, int out_size, void* d_ws, size_t ws_size,
                              hipStream_t stream) {
    const float* x    = (const float*)d_in[0];
    const float* W    = (const float*)d_in[1];
    const float* bias = (const float*)d_in[2];
    const int*   acts = (const int*)d_in[3];
    float* out = (float*)d_out;

    const int B = in_sizes[0] / NN_NIN;   // 65536
    const int num_tiles = B / 16;         // 4096

    // One wave per tile: 4096 waves = 1024 blocks of 256 threads (16 waves/CU).
    const int block = 256;
    const int waves_per_block = block / 64;
    const int grid = (num_tiles + waves_per_block - 1) / waves_per_block;

    NeuralNetwork_74466142978489_kernel<<<grid, block, 0, stream>>>(
        x, W, bias, acts, out, num_tiles);
}